// Round 2
// baseline (420.694 us; speedup 1.0000x reference)
//
#include <hip/hip_runtime.h>
#include <hip/hip_bf16.h>
#include <stdint.h>

#define BATCH   16384
#define IN_DIM  4096
#define OUT_DIM 64
#define MTILES  (BATCH/64)      // 256

// ---- main path: KI=32 chunks, double-buffered, SPLITK=8 ----
#define KI2     32
#define NCH2    (IN_DIM/KI2)    // 128 chunks
#define SPLITK  8
#define CPB2    (NCH2/SPLITK)   // 16 chunks per block
#define GRAN2   (OUT_DIM*13)    // 832 granules/chunk (13/row: 12 data + 1 pad)
#define CH2W    (GRAN2*8)       // 6656 shorts per chunk (13 KB, pad baked in)

// ---- fallback path (R3 structure, KI=64, SPLITK=4) ----
#define KI      64
#define KCH     (3*KI)          // 192
#define NCHUNK  (IN_DIM/KI)     // 64
#define FCPB    16
#define CHW     (OUT_DIM*KCH)   // 12288

typedef __attribute__((ext_vector_type(8))) short   short8;
typedef __attribute__((ext_vector_type(4))) float   floatx4;
typedef __attribute__((ext_vector_type(4))) uint32_t uintx4;

static __device__ __forceinline__ unsigned short f2bf(float f) {
    union { float f; uint32_t u; } v; v.f = f;
    uint32_t r = v.u + 0x7FFFu + ((v.u >> 16) & 1u);   // RNE
    return (unsigned short)(r >> 16);
}

// pack two floats -> packed bf16x2 (RNE) via v_cvt_pk_bf16_f32 (gfx950).
// NON-volatile asm: no side effects, stays schedulable (m240: volatile
// pinning was the -37%, the instruction itself is the fast path).
static __device__ __forceinline__ uint32_t pkrn(float lo, float hi) {
    uint32_t r;
    asm("v_cvt_pk_bf16_f32 %0, %1, %2" : "=v"(r) : "v"(lo), "v"(hi));
    return r;
}

// Degree-3 Cox-de Boor basis, knots [-1,-.5,0,.5,1,1], clamp-trick branchless-ish
static __device__ __forceinline__ void kan_features(float xv, float& b0, float& b1, float& sl) {
    float ax  = fabsf(xv);
    float axc = fminf(ax, 1.0f);
    float a2  = axc*axc;
    float om  = 1.0f - axc;
    float inner = __builtin_fmaf(__builtin_fmaf(4.0f, axc, -4.0f), a2, (2.0f/3.0f));
    float outer = (om*om) * (om * (4.0f/3.0f));
    b0 = (axc < 0.5f) ? inner : outer;
    float xc  = fminf(fmaxf(xv, -0.5f), 1.0f);        // v_med3
    float c3  = (xc < 0.0f) ? (4.0f/3.0f) : (-14.0f/3.0f);
    float mid = __builtin_fmaf(__builtin_fmaf(__builtin_fmaf(c3, xc, 2.0f), xc, 1.0f), xc, (1.0f/6.0f));
    float hi  = __builtin_fmaf(__builtin_fmaf(__builtin_fmaf(22.0f, xc, -48.0f), xc, 30.0f), xc, -4.0f) * (1.0f/3.0f);
    b1 = (xc < 0.5f) ? mid : hi;
    float e = __expf(-xv);
    sl = xv * __builtin_amdgcn_rcpf(1.0f + e);
}

// Pack weights, chunk-major, stride-13 granule rows (granule = 16 B = 8 il):
//   Wt[ci*CH2W + (j*13 + t*4 + ig)*8 + (il&7)]
//   t=0: c[i][j][0]*ws[i][j], t=1: c[i][j][1]*ws[i][j], t=2: wb[i][j]
__global__ __launch_bounds__(256) void kan_prep(
        const float* __restrict__ c, const float* __restrict__ ws,
        const float* __restrict__ wb, unsigned short* __restrict__ Wt) {
    int idx = blockIdx.x * 256 + threadIdx.x;     // 192 rows * 512 i-groups
    int row = idx >> 9;                           // j*3+t
    int i   = (idx & 511) << 3;                   // 8 consecutive input dims
    int j   = row / 3;
    int t   = row - j*3;
    int ci  = i >> 5;                             // 128 chunks of 32
    int ig  = (i & 31) >> 3;                      // granule within row-third
    float vv[8];
    #pragma unroll
    for (int e = 0; e < 8; e++) {
        int ii = i + e;
        if (t < 2) vv[e] = c[(size_t)ii*(OUT_DIM*2) + j*2 + t] * ws[(size_t)ii*OUT_DIM + j];
        else       vv[e] = wb[(size_t)ii*OUT_DIM + j];
    }
    uintx4 d;
    d[0] = pkrn(vv[0], vv[1]);
    d[1] = pkrn(vv[2], vv[3]);
    d[2] = pkrn(vv[4], vv[5]);
    d[3] = pkrn(vv[6], vv[7]);
    int g = j*13 + t*4 + ig;
    *(uintx4*)(Wt + (size_t)ci*CH2W + (size_t)g*8) = d;
}

// Cooperative staging of one 13 KB chunk: every wave issues exactly 4
// global_load_lds (3 full + 1 with 16 active lanes) so vmcnt counts are
// wave-uniform for the counted waits below.
static __device__ __forceinline__ void stage_chunk(
    const unsigned short* __restrict__ gW, unsigned short* dst,
    int wave, int lane)
{
    #pragma unroll
    for (int p = 0; p < 3; p++) {
        int g0 = p*256 + wave*64;
        __builtin_amdgcn_global_load_lds(
            (__attribute__((address_space(1))) void*)(gW + (size_t)(g0 + lane)*8),
            (__attribute__((address_space(3))) void*)(dst + (size_t)g0*8),
            16, 0, 0);
    }
    if (lane < 16)
        __builtin_amdgcn_global_load_lds(
            (__attribute__((address_space(1))) void*)(gW + (size_t)(768 + wave*16 + lane)*8),
            (__attribute__((address_space(3))) void*)(dst + (size_t)(768 + wave*16)*8),
            16, 0, 0);
}

// One chunk of the K-loop. Counted-vmcnt schedule (T4):
//  - stage next chunk (4 vm ops) + issue next x pair (2 vm ops, pinned asm)
//  - vmcnt(6): waits ONLY the previous chunk's x pair before features
//  - vmcnt(2) + raw s_barrier: staging complete, x pair stays in flight
//    ACROSS the barrier (the old __syncthreads vmcnt(0) drain ate ~200-300
//    cy of HBM latency per chunk, block-wide).
// sched_barrier(0) after each waitcnt per guide rule 18 (register-only
// features/MFMA must not hoist past an inline-asm waitcnt).
template<int BUF, bool DO_NEXT>
static __device__ __forceinline__ void chunk_body(
    int ci, const float* __restrict__ xrow,
    const unsigned short* __restrict__ Wt,
    unsigned short (&Bs)[2][CH2W],
    int wave, int lane, int m, int q,
    floatx4& xv0, floatx4& xv1, floatx4& xn0, floatx4& xn1,
    floatx4 (&acc)[4])
{
    if constexpr (DO_NEXT) {
        stage_chunk(Wt + (size_t)(ci + 1) * CH2W, &Bs[BUF ^ 1][0], wave, lane);
        __builtin_amdgcn_sched_barrier(0);
        const float* xp = xrow + (size_t)(ci + 1) * KI2 + q * 8;
        asm volatile(
            "global_load_dwordx4 %0, %2, off\n\t"
            "global_load_dwordx4 %1, %2, off offset:16"
            : "=&v"(xn0), "=&v"(xn1)
            : "v"(xp));
        // 6 newer vm ops in flight (4 stage + 2 x) -> waits exactly the
        // previous chunk's two x loads feeding xv0/xv1.
        asm volatile("s_waitcnt vmcnt(6)");
    } else {
        asm volatile("s_waitcnt vmcnt(0)");
    }
    __builtin_amdgcn_sched_barrier(0);

    // ---- features (pure VALU) ----
    uintx4 afu[3];   // t=0: B0, t=1: B1, t=2: silu ; 8 bf16 each
    #pragma unroll
    for (int w = 0; w < 4; w++) {
        float v0 = (w < 2) ? xv0[w*2]     : xv1[(w-2)*2];
        float v1 = (w < 2) ? xv0[w*2 + 1] : xv1[(w-2)*2 + 1];
        float b00, b10, s0, b01, b11, s1;
        kan_features(v0, b00, b10, s0);
        kan_features(v1, b01, b11, s1);
        afu[0][w] = pkrn(b00, b01);
        afu[1][w] = pkrn(b10, b11);
        afu[2][w] = pkrn(s0, s1);
    }

    // ---- MFMA from current buffer ----
    #pragma unroll
    for (int t = 0; t < 3; t++) {
        #pragma unroll
        for (int n = 0; n < 4; n++) {
            const int j = n*16 + m;
            short8 bf = *(const short8*)&Bs[BUF][(size_t)(j*13 + t*4 + q)*8];
            acc[n] = __builtin_amdgcn_mfma_f32_16x16x32_bf16(
                __builtin_bit_cast(short8, afu[t]), bf, acc[n], 0, 0, 0);
        }
    }

    if constexpr (DO_NEXT) {
        __builtin_amdgcn_sched_barrier(0);
        asm volatile("s_waitcnt vmcnt(2)");   // staging done; x pair stays in flight
        __builtin_amdgcn_sched_barrier(0);
        __builtin_amdgcn_s_barrier();
        __builtin_amdgcn_sched_barrier(0);
    }
}

// Main: double-buffered LDS, counted-vmcnt barriers, partials to pbuf.
__global__ __launch_bounds__(256, 6) void kan_main_pre(
    const float* __restrict__ x, const unsigned short* __restrict__ Wt,
    float* __restrict__ pbuf)
{
    __shared__ unsigned short Bs[2][CH2W];   // 2 x 13 KB

    const int tid  = threadIdx.x;
    const int wave = tid >> 6;
    const int lane = tid & 63;
    const int m    = lane & 15;
    const int q    = lane >> 4;
    const int mt   = blockIdx.x & (MTILES - 1);
    const int kh   = blockIdx.x >> 8;                // SPLITK group 0..7
    const int r    = mt*64 + wave*16 + m;
    const float* xrow = x + (size_t)r * IN_DIM;
    const int ci0 = kh * CPB2;

    floatx4 acc[4] = {};

    // preload x for chunk 0 (drained by the one full __syncthreads below)
    floatx4 xv0 = *(const floatx4*)(xrow + ci0*KI2 + q*8);
    floatx4 xv1 = *(const floatx4*)(xrow + ci0*KI2 + q*8 + 4);
    floatx4 xn0 = {}, xn1 = {};

    stage_chunk(Wt + (size_t)ci0 * CH2W, &Bs[0][0], wave, lane);
    __syncthreads();

    // manual 2x unroll: register roles swap so the prefetch pair never
    // needs a copy (a tail copy would force a vmcnt wait before the barrier)
    for (int cp = 0; cp < CPB2 - 2; cp += 2) {
        chunk_body<0, true>(ci0+cp,   xrow, Wt, Bs, wave, lane, m, q, xv0, xv1, xn0, xn1, acc);
        chunk_body<1, true>(ci0+cp+1, xrow, Wt, Bs, wave, lane, m, q, xn0, xn1, xv0, xv1, acc);
    }
    chunk_body<0, true >(ci0+CPB2-2, xrow, Wt, Bs, wave, lane, m, q, xv0, xv1, xn0, xn1, acc);
    chunk_body<1, false>(ci0+CPB2-1, xrow, Wt, Bs, wave, lane, m, q, xn0, xn1, xv0, xv1, acc);

    // ---- coalesced partial store: P[kh][mt][n][tid] as floatx4 ----
    float* pb = pbuf + (((size_t)kh*MTILES + mt)*4)*1024;
    #pragma unroll
    for (int n = 0; n < 4; n++)
        *(floatx4*)(pb + ((size_t)n*256 + tid)*4) = acc[n];
}

// Sum SPLITK partials -> out.  C/D layout: col=lane&15, row=quad*4+reg.
__global__ __launch_bounds__(256) void kan_reduce(
    const float* __restrict__ pbuf, float* __restrict__ out)
{
    const int mt   = blockIdx.x;
    const int tid  = threadIdx.x;
    const int wave = tid >> 6;
    const int lane = tid & 63;
    const int m    = lane & 15;
    const int q    = lane >> 4;
    #pragma unroll
    for (int n = 0; n < 4; n++) {
        floatx4 s = {};
        #pragma unroll
        for (int p = 0; p < SPLITK; p++) {
            floatx4 v = *(const floatx4*)(pbuf +
                (((size_t)p*MTILES + mt)*4 + n)*1024 + (size_t)tid*4);
            s += v;
        }
        #pragma unroll
        for (int reg = 0; reg < 4; reg++) {
            int orow = mt*64 + wave*16 + q*4 + reg;
            out[(size_t)orow*OUT_DIM + n*16 + m] = s[reg];
        }
    }
}

// ---------------- fallback (tiny ws): R3 path with atomics ----------------
__global__ __launch_bounds__(256, 4) void kan_main_fb(
    const float* __restrict__ x, const float* __restrict__ c,
    const float* __restrict__ ws, const float* __restrict__ wb,
    float* __restrict__ out)
{
    __shared__ unsigned short Bsf[CHW];
    const int tid  = threadIdx.x;
    const int wave = tid >> 6;
    const int lane = tid & 63;
    const int m    = lane & 15;
    const int q    = lane >> 4;
    const int mt   = blockIdx.x & (MTILES - 1);
    const int kh   = blockIdx.x >> 8;
    const int row0 = mt * 64;
    const int r    = row0 + wave*16 + m;
    const float* xrow = x + (size_t)r * IN_DIM;
    floatx4 acc[4] = {};
    for (int cc = 0; cc < FCPB; cc++) {
        const int i0 = (kh * FCPB + cc) * KI;
        floatx4 xv[4];
        xv[0] = *(const floatx4*)(xrow + i0 + q*8);
        xv[1] = *(const floatx4*)(xrow + i0 + q*8 + 4);
        xv[2] = *(const floatx4*)(xrow + i0 + 32 + q*8);
        xv[3] = *(const floatx4*)(xrow + i0 + 32 + q*8 + 4);
        uintx4 afu[6];
        #pragma unroll
        for (int g = 0; g < 2; g++) {
            #pragma unroll
            for (int w = 0; w < 4; w++) {
                float v0 = xv[g*2 + (w >> 1)][(w & 1)*2 + 0];
                float v1 = xv[g*2 + (w >> 1)][(w & 1)*2 + 1];
                float b00, b10, sl0, b01, b11, sl1;
                kan_features(v0, b00, b10, sl0);
                kan_features(v1, b01, b11, sl1);
                afu[0 + g][w] = pkrn(b00, b01);
                afu[2 + g][w] = pkrn(b10, b11);
                afu[4 + g][w] = pkrn(sl0, sl1);
            }
        }
        __syncthreads();
        #pragma unroll
        for (int p = 0; p < 16; p++) {
            int idx = tid + p*256;
            int j = idx & 63, i = idx >> 6;
            int gi = i0 + i;
            const float* cp = c + ((size_t)gi*OUT_DIM + j)*2;
            float c0 = cp[0], c1 = cp[1];
            float sw = ws[(size_t)gi*OUT_DIM + j];
            float b  = wb[(size_t)gi*OUT_DIM + j];
            int jx = j & 7;
            Bsf[j*KCH + ((0*8 + (i>>3)) ^ jx)*8 + (i&7)] = f2bf(c0*sw);
            Bsf[j*KCH + ((1*8 + (i>>3)) ^ jx)*8 + (i&7)] = f2bf(c1*sw);
            Bsf[j*KCH + ((2*8 + (i>>3)) ^ jx)*8 + (i&7)] = f2bf(b);
        }
        __syncthreads();
        #pragma unroll
        for (int s = 0; s < 6; s++) {
            const int kb = (s >> 1)*8 + (s & 1)*4 + q;
            #pragma unroll
            for (int n = 0; n < 4; n++) {
                const int j = n*16 + m;
                short8 bf = *(const short8*)&Bsf[j*KCH + ((kb ^ (j & 7)) << 3)];
                acc[n] = __builtin_amdgcn_mfma_f32_16x16x32_bf16(
                    __builtin_bit_cast(short8, afu[s]), bf, acc[n], 0, 0, 0);
            }
        }
    }
    #pragma unroll
    for (int n = 0; n < 4; n++)
        #pragma unroll
        for (int reg = 0; reg < 4; reg++) {
            int orow = row0 + wave*16 + q*4 + reg;
            atomicAdd(&out[(size_t)orow*OUT_DIM + n*16 + m], acc[n][reg]);
        }
}

extern "C" void kernel_launch(void* const* d_in, const int* in_sizes, int n_in,
                              void* d_out, int out_size, void* d_ws, size_t ws_size,
                              hipStream_t stream) {
    const float* x  = (const float*)d_in[0];
    const float* c  = (const float*)d_in[1];
    const float* ws = (const float*)d_in[2];
    const float* wb = (const float*)d_in[3];
    float* out = (float*)d_out;

    const size_t part_bytes = (size_t)SPLITK * BATCH * OUT_DIM * sizeof(float); // 32 MB
    const size_t wt_bytes   = (size_t)NCH2 * CH2W * sizeof(unsigned short);     // 1.7 MB
    if (ws_size >= part_bytes + wt_bytes) {
        float* pbuf = (float*)d_ws;
        unsigned short* Wt = (unsigned short*)((char*)d_ws + part_bytes);
        kan_prep<<<384, 256, 0, stream>>>(c, ws, wb, Wt);
        kan_main_pre<<<MTILES * SPLITK, 256, 0, stream>>>(x, Wt, pbuf);
        kan_reduce<<<MTILES, 256, 0, stream>>>(pbuf, out);
    } else {
        (void)hipMemsetAsync(d_out, 0, (size_t)out_size * sizeof(float), stream);
        kan_main_fb<<<MTILES * 4, 256, 0, stream>>>(x, c, ws, wb, out);
    }
}

// Round 3
// 402.879 us; speedup vs baseline: 1.0442x; 1.0442x over previous
//
#include <hip/hip_runtime.h>
#include <hip/hip_bf16.h>
#include <stdint.h>

#define BATCH   16384
#define IN_DIM  4096
#define OUT_DIM 64
#define MTILES  (BATCH/64)      // 256

// ---- main path: KI=32 chunks, double-buffered, SPLITK=8 ----
#define KI2     32
#define NCH2    (IN_DIM/KI2)    // 128 chunks
#define SPLITK  8
#define CPB2    (NCH2/SPLITK)   // 16 chunks per block
#define GRAN2   (OUT_DIM*13)    // 832 granules/chunk (13/row: 12 data + 1 pad)
#define CH2W    (GRAN2*8)       // 6656 shorts per chunk (13 KB, pad baked in)

// ---- fallback path (R3 structure, KI=64, SPLITK=4) ----
#define KI      64
#define KCH     (3*KI)          // 192
#define NCHUNK  (IN_DIM/KI)     // 64
#define FCPB    16
#define CHW     (OUT_DIM*KCH)   // 12288

typedef __attribute__((ext_vector_type(8))) short   short8;
typedef __attribute__((ext_vector_type(4))) float   floatx4;
typedef __attribute__((ext_vector_type(4))) uint32_t uintx4;

static __device__ __forceinline__ unsigned short f2bf(float f) {
    union { float f; uint32_t u; } v; v.f = f;
    uint32_t r = v.u + 0x7FFFu + ((v.u >> 16) & 1u);   // RNE
    return (unsigned short)(r >> 16);
}

// pack two floats -> packed bf16x2 (RNE) via v_cvt_pk_bf16_f32 (gfx950).
// NON-volatile, no clobbers: stays schedulable/CSE-able. Replaces ~7
// integer VALU ops per pair with 1 instruction.
static __device__ __forceinline__ uint32_t pkrn(float lo, float hi) {
    uint32_t r;
    asm("v_cvt_pk_bf16_f32 %0, %1, %2" : "=v"(r) : "v"(lo), "v"(hi));
    return r;
}

// Degree-3 Cox-de Boor basis, knots [-1,-.5,0,.5,1,1], clamp-trick branchless-ish:
//  B0 via axc=min(|x|,1):  axc<.5: 4axc^3-4axc^2+2/3 ; else (4/3)(1-axc)^3  (0 at axc=1)
//  B1 via xc=med3(x,-.5,1): xc<.5: ((c3*xc+2)xc+1)xc+1/6 (c3 = x<0 ? 4/3 : -14/3)
//                           else (22xc^3-48xc^2+30xc-4)/3   (mid(-.5)=0, hi(1)=0)
static __device__ __forceinline__ void kan_features(float xv, float& b0, float& b1, float& sl) {
    float ax  = fabsf(xv);
    float axc = fminf(ax, 1.0f);
    float a2  = axc*axc;
    float om  = 1.0f - axc;
    float inner = __builtin_fmaf(__builtin_fmaf(4.0f, axc, -4.0f), a2, (2.0f/3.0f));
    float outer = (om*om) * (om * (4.0f/3.0f));
    b0 = (axc < 0.5f) ? inner : outer;
    float xc  = fminf(fmaxf(xv, -0.5f), 1.0f);        // v_med3
    float c3  = (xc < 0.0f) ? (4.0f/3.0f) : (-14.0f/3.0f);
    float mid = __builtin_fmaf(__builtin_fmaf(__builtin_fmaf(c3, xc, 2.0f), xc, 1.0f), xc, (1.0f/6.0f));
    float hi  = __builtin_fmaf(__builtin_fmaf(__builtin_fmaf(22.0f, xc, -48.0f), xc, 30.0f), xc, -4.0f) * (1.0f/3.0f);
    b1 = (xc < 0.5f) ? mid : hi;
    float e = __expf(-xv);
    sl = xv * __builtin_amdgcn_rcpf(1.0f + e);
}

// Pack weights, chunk-major, stride-13 granule rows (granule = 16 B = 8 il):
//   Wt[ci*CH2W + (j*13 + t*4 + ig)*8 + (il&7)]
//   t=0: c[i][j][0]*ws[i][j], t=1: c[i][j][1]*ws[i][j], t=2: wb[i][j]
__global__ __launch_bounds__(256) void kan_prep(
        const float* __restrict__ c, const float* __restrict__ ws,
        const float* __restrict__ wb, unsigned short* __restrict__ Wt) {
    int idx = blockIdx.x * 256 + threadIdx.x;     // 192 rows * 512 i-groups
    int row = idx >> 9;                           // j*3+t
    int i   = (idx & 511) << 3;                   // 8 consecutive input dims
    int j   = row / 3;
    int t   = row - j*3;
    int ci  = i >> 5;                             // 128 chunks of 32
    int ig  = (i & 31) >> 3;                      // granule within row-third
    float vv[8];
    #pragma unroll
    for (int e = 0; e < 8; e++) {
        int ii = i + e;
        if (t < 2) vv[e] = c[(size_t)ii*(OUT_DIM*2) + j*2 + t] * ws[(size_t)ii*OUT_DIM + j];
        else       vv[e] = wb[(size_t)ii*OUT_DIM + j];
    }
    uintx4 d;
    d[0] = pkrn(vv[0], vv[1]);
    d[1] = pkrn(vv[2], vv[3]);
    d[2] = pkrn(vv[4], vv[5]);
    d[3] = pkrn(vv[6], vv[7]);
    int g = j*13 + t*4 + ig;
    *(uintx4*)(Wt + (size_t)ci*CH2W + (size_t)g*8) = d;
}

// Main: double-buffered LDS, one barrier per chunk, partials to pbuf.
// (Proven 402 us schedule — compiler-managed waitcnts. The R2 counted-vmcnt
// + sched_barrier variant regressed ~20 us: m141-style scheduler
// fragmentation. Do not re-pin.)
__global__ __launch_bounds__(256, 6) void kan_main_pre(
    const float* __restrict__ x, const unsigned short* __restrict__ Wt,
    float* __restrict__ pbuf)
{
    __shared__ unsigned short Bs[2][CH2W];   // 2 x 13 KB

    const int tid  = threadIdx.x;
    const int wave = tid >> 6;
    const int lane = tid & 63;
    const int m    = lane & 15;
    const int q    = lane >> 4;
    const int mt   = blockIdx.x & (MTILES - 1);
    const int kh   = blockIdx.x >> 8;                // SPLITK group 0..7
    const int row0 = mt * 64;
    const int r    = row0 + wave*16 + m;
    const float* xrow = x + (size_t)r * IN_DIM;
    const int ci0 = kh * CPB2;

    floatx4 acc[4] = {};

    // preload x for chunk 0
    floatx4 xv0 = *(const floatx4*)(xrow + ci0*KI2 + q*8);
    floatx4 xv1 = *(const floatx4*)(xrow + ci0*KI2 + q*8 + 4);

    // stage chunk 0 -> buffer 0 (832 granules, lane-linear DMA)
    {
        const unsigned short* gW = Wt + (size_t)ci0 * CH2W;
        #pragma unroll
        for (int p = 0; p < 3; p++) {
            int g0 = p*256 + wave*64;
            __builtin_amdgcn_global_load_lds(
                (__attribute__((address_space(1))) void*)(gW + (size_t)(g0 + lane)*8),
                (__attribute__((address_space(3))) void*)(&Bs[0][0] + (size_t)g0*8),
                16, 0, 0);
        }
        if (tid < 64)
            __builtin_amdgcn_global_load_lds(
                (__attribute__((address_space(1))) void*)(gW + (size_t)(768 + lane)*8),
                (__attribute__((address_space(3))) void*)(&Bs[0][0] + (size_t)768*8),
                16, 0, 0);
    }
    __syncthreads();

    for (int cc = 0; cc < CPB2; cc++) {
        const int buf = cc & 1;
        const int ci  = ci0 + cc;

        // ---- stage NEXT chunk into other buffer (drains at end barrier) ----
        if (cc + 1 < CPB2) {
            const unsigned short* gW = Wt + (size_t)(ci + 1) * CH2W;
            #pragma unroll
            for (int p = 0; p < 3; p++) {
                int g0 = p*256 + wave*64;
                __builtin_amdgcn_global_load_lds(
                    (__attribute__((address_space(1))) void*)(gW + (size_t)(g0 + lane)*8),
                    (__attribute__((address_space(3))) void*)(&Bs[buf^1][0] + (size_t)g0*8),
                    16, 0, 0);
            }
            if (tid < 64)
                __builtin_amdgcn_global_load_lds(
                    (__attribute__((address_space(1))) void*)(gW + (size_t)(768 + lane)*8),
                    (__attribute__((address_space(3))) void*)(&Bs[buf^1][0] + (size_t)768*8),
                    16, 0, 0);
        }

        // ---- prefetch next chunk's x (HBM; hidden by features+MFMA) ----
        const int inx = (cc + 1 < CPB2) ? (ci + 1)*KI2 : ci*KI2;
        floatx4 xn0 = *(const floatx4*)(xrow + inx + q*8);
        floatx4 xn1 = *(const floatx4*)(xrow + inx + q*8 + 4);

        // ---- features (pure VALU) ----
        uintx4 afu[3];   // t=0: B0, t=1: B1, t=2: silu ; 8 bf16 each
        #pragma unroll
        for (int w = 0; w < 4; w++) {
            float v0 = (w < 2) ? xv0[w*2]     : xv1[(w-2)*2];
            float v1 = (w < 2) ? xv0[w*2 + 1] : xv1[(w-2)*2 + 1];
            float b00, b10, s0, b01, b11, s1;
            kan_features(v0, b00, b10, s0);
            kan_features(v1, b01, b11, s1);
            afu[0][w] = pkrn(b00, b01);
            afu[1][w] = pkrn(b10, b11);
            afu[2][w] = pkrn(s0, s1);
        }

        // ---- MFMA from current buffer ----
        #pragma unroll
        for (int t = 0; t < 3; t++) {
            #pragma unroll
            for (int n = 0; n < 4; n++) {
                const int j = n*16 + m;
                short8 bf = *(const short8*)&Bs[buf][(size_t)(j*13 + t*4 + q)*8];
                acc[n] = __builtin_amdgcn_mfma_f32_16x16x32_bf16(
                    __builtin_bit_cast(short8, afu[t]), bf, acc[n], 0, 0, 0);
            }
        }

        xv0 = xn0; xv1 = xn1;
        __syncthreads();   // buf readers done + buf^1 staging drained
    }

    // ---- coalesced partial store: P[kh][mt][n][tid] as floatx4 ----
    float* pb = pbuf + (((size_t)kh*MTILES + mt)*4)*1024;
    #pragma unroll
    for (int n = 0; n < 4; n++)
        *(floatx4*)(pb + ((size_t)n*256 + tid)*4) = acc[n];
}

// Sum SPLITK partials -> out.  C/D layout: col=lane&15, row=quad*4+reg.
__global__ __launch_bounds__(256) void kan_reduce(
    const float* __restrict__ pbuf, float* __restrict__ out)
{
    const int mt   = blockIdx.x;
    const int tid  = threadIdx.x;
    const int wave = tid >> 6;
    const int lane = tid & 63;
    const int m    = lane & 15;
    const int q    = lane >> 4;
    #pragma unroll
    for (int n = 0; n < 4; n++) {
        floatx4 s = {};
        #pragma unroll
        for (int p = 0; p < SPLITK; p++) {
            floatx4 v = *(const floatx4*)(pbuf +
                (((size_t)p*MTILES + mt)*4 + n)*1024 + (size_t)tid*4);
            s += v;
        }
        #pragma unroll
        for (int reg = 0; reg < 4; reg++) {
            int orow = mt*64 + wave*16 + q*4 + reg;
            out[(size_t)orow*OUT_DIM + n*16 + m] = s[reg];
        }
    }
}

// ---------------- fallback (tiny ws): R3 path with atomics ----------------
__global__ __launch_bounds__(256, 4) void kan_main_fb(
    const float* __restrict__ x, const float* __restrict__ c,
    const float* __restrict__ ws, const float* __restrict__ wb,
    float* __restrict__ out)
{
    __shared__ unsigned short Bsf[CHW];
    const int tid  = threadIdx.x;
    const int wave = tid >> 6;
    const int lane = tid & 63;
    const int m    = lane & 15;
    const int q    = lane >> 4;
    const int mt   = blockIdx.x & (MTILES - 1);
    const int kh   = blockIdx.x >> 8;
    const int row0 = mt * 64;
    const int r    = row0 + wave*16 + m;
    const float* xrow = x + (size_t)r * IN_DIM;
    floatx4 acc[4] = {};
    for (int cc = 0; cc < FCPB; cc++) {
        const int i0 = (kh * FCPB + cc) * KI;
        floatx4 xv[4];
        xv[0] = *(const floatx4*)(xrow + i0 + q*8);
        xv[1] = *(const floatx4*)(xrow + i0 + q*8 + 4);
        xv[2] = *(const floatx4*)(xrow + i0 + 32 + q*8);
        xv[3] = *(const floatx4*)(xrow + i0 + 32 + q*8 + 4);
        uintx4 afu[6];
        #pragma unroll
        for (int g = 0; g < 2; g++) {
            #pragma unroll
            for (int w = 0; w < 4; w++) {
                float v0 = xv[g*2 + (w >> 1)][(w & 1)*2 + 0];
                float v1 = xv[g*2 + (w >> 1)][(w & 1)*2 + 1];
                float b00, b10, sl0, b01, b11, sl1;
                kan_features(v0, b00, b10, sl0);
                kan_features(v1, b01, b11, sl1);
                afu[0 + g][w] = pkrn(b00, b01);
                afu[2 + g][w] = pkrn(b10, b11);
                afu[4 + g][w] = pkrn(sl0, sl1);
            }
        }
        __syncthreads();
        #pragma unroll
        for (int p = 0; p < 16; p++) {
            int idx = tid + p*256;
            int j = idx & 63, i = idx >> 6;
            int gi = i0 + i;
            const float* cp = c + ((size_t)gi*OUT_DIM + j)*2;
            float c0 = cp[0], c1 = cp[1];
            float sw = ws[(size_t)gi*OUT_DIM + j];
            float b  = wb[(size_t)gi*OUT_DIM + j];
            int jx = j & 7;
            Bsf[j*KCH + ((0*8 + (i>>3)) ^ jx)*8 + (i&7)] = f2bf(c0*sw);
            Bsf[j*KCH + ((1*8 + (i>>3)) ^ jx)*8 + (i&7)] = f2bf(c1*sw);
            Bsf[j*KCH + ((2*8 + (i>>3)) ^ jx)*8 + (i&7)] = f2bf(b);
        }
        __syncthreads();
        #pragma unroll
        for (int s = 0; s < 6; s++) {
            const int kb = (s >> 1)*8 + (s & 1)*4 + q;
            #pragma unroll
            for (int n = 0; n < 4; n++) {
                const int j = n*16 + m;
                short8 bf = *(const short8*)&Bsf[j*KCH + ((kb ^ (j & 7)) << 3)];
                acc[n] = __builtin_amdgcn_mfma_f32_16x16x32_bf16(
                    __builtin_bit_cast(short8, afu[s]), bf, acc[n], 0, 0, 0);
            }
        }
    }
    #pragma unroll
    for (int n = 0; n < 4; n++)
        #pragma unroll
        for (int reg = 0; reg < 4; reg++) {
            int orow = row0 + wave*16 + q*4 + reg;
            atomicAdd(&out[(size_t)orow*OUT_DIM + n*16 + m], acc[n][reg]);
        }
}

extern "C" void kernel_launch(void* const* d_in, const int* in_sizes, int n_in,
                              void* d_out, int out_size, void* d_ws, size_t ws_size,
                              hipStream_t stream) {
    const float* x  = (const float*)d_in[0];
    const float* c  = (const float*)d_in[1];
    const float* ws = (const float*)d_in[2];
    const float* wb = (const float*)d_in[3];
    float* out = (float*)d_out;

    const size_t part_bytes = (size_t)SPLITK * BATCH * OUT_DIM * sizeof(float); // 32 MB
    const size_t wt_bytes   = (size_t)NCH2 * CH2W * sizeof(unsigned short);     // 1.7 MB
    if (ws_size >= part_bytes + wt_bytes) {
        float* pbuf = (float*)d_ws;
        unsigned short* Wt = (unsigned short*)((char*)d_ws + part_bytes);
        kan_prep<<<384, 256, 0, stream>>>(c, ws, wb, Wt);
        kan_main_pre<<<MTILES * SPLITK, 256, 0, stream>>>(x, Wt, pbuf);
        kan_reduce<<<MTILES, 256, 0, stream>>>(pbuf, out);
    } else {
        (void)hipMemsetAsync(d_out, 0, (size_t)out_size * sizeof(float), stream);
        kan_main_fb<<<MTILES * 4, 256, 0, stream>>>(x, c, ws, wb, out);
    }
}